// Round 1
// baseline (429.397 us; speedup 1.0000x reference)
//
#include <hip/hip_runtime.h>
#include <math.h>

#define TI 16          // i-rows per block
#define BLOCK 1024     // threads per block (16 waves)
#define DIM 16         // embedding dim (fixed by problem)

__global__ __launch_bounds__(BLOCK) void pair_kernel(
    const float* __restrict__ z, const float* __restrict__ W,
    const int* __restrict__ idx, int B, int N, double* __restrict__ ws)
{
    __shared__ float zi[TI][DIM];     // broadcast reads -> no bank conflicts
    __shared__ float sqi_s[TI];       // raw squared norm (for sqdist)
    __shared__ float rai_s[TI];       // 1/(1 - clamped norm)
    __shared__ int   idr_s[TI];
    __shared__ double red[BLOCK / 64][4];

    const int tid = threadIdx.x;
    const int i0  = blockIdx.x * TI;

    if (tid < TI) {
        int row = i0 + tid;
        idr_s[tid] = idx[row];
        float s = 0.f;
        #pragma unroll
        for (int k = 0; k < DIM; ++k) {
            float v = z[(size_t)row * DIM + k];
            zi[tid][k] = v;
            s = fmaf(v, v, s);
        }
        sqi_s[tid] = s;
        float sc = fminf(fmaxf(s, 0.f), 0.99999f);   // clamp to 1 - 1e-5
        rai_s[tid] = 1.0f / (1.0f - sc);
    }
    __syncthreads();

    // hoist per-row gather indices into registers
    int idr[TI];
    #pragma unroll
    for (int ii = 0; ii < TI; ++ii) idr[ii] = idr_s[ii];

    double s_wd = 0.0, s_w = 0.0, s_rep = 0.0;
    long long cnt = 0;

    for (int sub = 0; sub < B; sub += BLOCK) {
        const int j = sub + tid;
        // z_j into registers (vectorized, 64B/thread)
        float zj[DIM];
        const float4* zp = reinterpret_cast<const float4*>(z + (size_t)j * DIM);
        #pragma unroll
        for (int q = 0; q < 4; ++q) {
            float4 v = zp[q];
            zj[4*q+0] = v.x; zj[4*q+1] = v.y; zj[4*q+2] = v.z; zj[4*q+3] = v.w;
        }
        float sj = 0.f;
        #pragma unroll
        for (int k = 0; k < DIM; ++k) sj = fmaf(zj[k], zj[k], sj);
        float scj = fminf(fmaxf(sj, 0.f), 0.99999f);
        float rj  = 1.0f / (1.0f - scj);
        const int ij = idx[j];

        // 16 independent gathers, issued together for latency hiding
        float wv[TI];
        #pragma unroll
        for (int ii = 0; ii < TI; ++ii)
            wv[ii] = W[(size_t)idr[ii] * (size_t)N + (size_t)ij];

        #pragma unroll
        for (int ii = 0; ii < TI; ++ii) {
            float dot = 0.f;
            #pragma unroll
            for (int k = 0; k < DIM; ++k) dot = fmaf(zi[ii][k], zj[k], dot);
            float sqd = fmaxf(sqi_s[ii] + sj - 2.0f * dot, 0.0f);
            float x = fmaf(sqd * rai_s[ii] * rj, 2.0f, 1.0f);
            float t = sqrtf(fmaxf(fmaf(x, x, -1.0f), 1e-10f));
            float y = x + t;                       // d = log(y); exp(-d) = 1/y
            bool diag = ((i0 + ii) == j);
            float w = wv[ii];
            if (!diag) {
                if (w != 0.0f) {
                    s_wd += (double)(w * logf(y));
                    s_w  += (double)w;
                } else {
                    s_rep += (double)(1.0f / y);
                    cnt++;
                }
            }
        }
    }

    // wave-level reduce (64 lanes), then cross-wave via LDS, one atomic set per block
    double vals[4] = { s_wd, s_w, s_rep, (double)cnt };
    #pragma unroll
    for (int c = 0; c < 4; ++c) {
        double v = vals[c];
        for (int off = 32; off > 0; off >>= 1) v += __shfl_down(v, off);
        vals[c] = v;
    }
    const int wid = tid >> 6, lane = tid & 63;
    if (lane == 0) {
        #pragma unroll
        for (int c = 0; c < 4; ++c) red[wid][c] = vals[c];
    }
    __syncthreads();
    if (tid == 0) {
        double tot[4] = {0.0, 0.0, 0.0, 0.0};
        for (int wgt = 0; wgt < BLOCK / 64; ++wgt)
            for (int c = 0; c < 4; ++c) tot[c] += red[wgt][c];
        for (int c = 0; c < 4; ++c) atomicAdd(&ws[c], tot[c]);
    }
}

__global__ void finish_kernel(const double* __restrict__ ws, float* __restrict__ out)
{
    double la = ws[0] / (ws[1] + 1e-8);
    double lr = ws[2] / (ws[3] + 1e-8);
    out[0] = (float)(la + lr);
}

extern "C" void kernel_launch(void* const* d_in, const int* in_sizes, int n_in,
                              void* d_out, int out_size, void* d_ws, size_t ws_size,
                              hipStream_t stream)
{
    const float* z  = (const float*)d_in[0];
    const float* W  = (const float*)d_in[1];
    const int* idx  = (const int*)d_in[2];
    const int B = in_sizes[2];                       // 4096
    // N from W element count (N*N)
    int N = 1;
    while ((long long)(N + 1) * (N + 1) <= (long long)in_sizes[1]) ++N;

    double* ws = (double*)d_ws;
    hipMemsetAsync(ws, 0, 4 * sizeof(double), stream);

    dim3 grid(B / TI);
    pair_kernel<<<grid, BLOCK, 0, stream>>>(z, W, idx, B, N, ws);
    finish_kernel<<<1, 1, 0, stream>>>(ws, (float*)d_out);
}